// Round 1
// baseline (468.506 us; speedup 1.0000x reference)
//
#include <hip/hip_runtime.h>
#include <math.h>

#define NFEAT 512
#define NHID  128
#define NCLASS 16
#define SCAN_BS 512

// ---------------- CSR build ----------------

__global__ void k_init_deg(int* __restrict__ deg, int n) {
    int i = blockIdx.x * blockDim.x + threadIdx.x;
    if (i < n) deg[i] = 1;  // self-loop
}

__global__ void k_count(const int* __restrict__ dst, int e, int* __restrict__ deg) {
    int i = blockIdx.x * blockDim.x + threadIdx.x;
    if (i < e) atomicAdd(&deg[dst[i]], 1);
}

__global__ void k_dinv(const int* __restrict__ deg, float* __restrict__ dinv,
                       int* __restrict__ cursor, int n) {
    int i = blockIdx.x * blockDim.x + threadIdx.x;
    if (i < n) {
        dinv[i] = rsqrtf((float)deg[i]);
        cursor[i] = 0;
    }
}

__global__ void k_scan1(const int* __restrict__ deg, int* __restrict__ offs,
                        int* __restrict__ bsum, int n) {
    __shared__ int s[SCAN_BS];
    int t = threadIdx.x;
    int i = blockIdx.x * SCAN_BS + t;
    int v = (i < n) ? deg[i] : 0;
    s[t] = v;
    for (int off = 1; off < SCAN_BS; off <<= 1) {
        __syncthreads();
        int x = (t >= off) ? s[t - off] : 0;
        __syncthreads();
        s[t] += x;
    }
    __syncthreads();
    if (i < n) offs[i] = s[t] - v;  // exclusive within block
    if (t == SCAN_BS - 1) bsum[blockIdx.x] = s[t];
}

__global__ void k_scan2(int* __restrict__ bsum, int* __restrict__ offs, int nb, int n) {
    if (threadIdx.x == 0 && blockIdx.x == 0) {
        int run = 0;
        for (int b = 0; b < nb; b++) { int x = bsum[b]; bsum[b] = run; run += x; }
        offs[n] = run;  // = E + N
    }
}

__global__ void k_scan3(int* __restrict__ offs, const int* __restrict__ bsum, int n) {
    int i = blockIdx.x * SCAN_BS + threadIdx.x;
    if (i < n) offs[i] += bsum[blockIdx.x];
}

__global__ void k_fill_edges(const int* __restrict__ src, const int* __restrict__ dst, int e,
                             const int* __restrict__ offs, int* __restrict__ cursor,
                             int* __restrict__ col) {
    int i = blockIdx.x * blockDim.x + threadIdx.x;
    if (i < e) {
        int d = dst[i];
        int p = atomicAdd(&cursor[d], 1);
        col[offs[d] + p] = src[i];
    }
}

__global__ void k_fill_self(const int* __restrict__ offs, int* __restrict__ cursor,
                            int* __restrict__ col, int n) {
    int i = blockIdx.x * blockDim.x + threadIdx.x;
    if (i < n) {
        int p = atomicAdd(&cursor[i], 1);
        col[offs[i] + p] = i;
    }
}

// ---------------- f32 tiled GEMM: H[M,128] = X[M,K] @ W[K,128] ----------------
// block: 256 threads, tile 64 rows x 128 cols, BK=32

__global__ __launch_bounds__(256) void k_gemm(const float* __restrict__ X,
                                              const float* __restrict__ W,
                                              float* __restrict__ H, int M, int K) {
    __shared__ float Xs[64][33];   // +1 pad: conflict-free column reads
    __shared__ float Ws[32][128];
    int tid = threadIdx.x;
    int tx = tid & 15;        // col group: cols tx + 16*j
    int ty = tid >> 4;        // row group: rows ty + 16*i
    int rowbase = blockIdx.x * 64;

    float acc[4][8];
#pragma unroll
    for (int i = 0; i < 4; i++)
#pragma unroll
        for (int j = 0; j < 8; j++) acc[i][j] = 0.f;

    for (int k0 = 0; k0 < K; k0 += 32) {
        // load X tile: 64x32 = 512 float4, 2 per thread
#pragma unroll
        for (int t = 0; t < 2; t++) {
            int idx = tid + t * 256;
            int r = idx >> 3, c4 = idx & 7;
            int gr = rowbase + r;
            float4 v = make_float4(0.f, 0.f, 0.f, 0.f);
            if (gr < M) v = *(const float4*)(X + (size_t)gr * K + k0 + c4 * 4);
            Xs[r][c4 * 4 + 0] = v.x;
            Xs[r][c4 * 4 + 1] = v.y;
            Xs[r][c4 * 4 + 2] = v.z;
            Xs[r][c4 * 4 + 3] = v.w;
        }
        // load W tile: 32x128 = 1024 float4, 4 per thread
#pragma unroll
        for (int t = 0; t < 4; t++) {
            int idx = tid + t * 256;
            int r = idx >> 5, c4 = idx & 31;
            float4 v = *(const float4*)(W + (size_t)(k0 + r) * 128 + c4 * 4);
            *(float4*)&Ws[r][c4 * 4] = v;
        }
        __syncthreads();
#pragma unroll 8
        for (int kk = 0; kk < 32; kk++) {
            float xr[4], wr[8];
#pragma unroll
            for (int i = 0; i < 4; i++) xr[i] = Xs[ty + 16 * i][kk];
#pragma unroll
            for (int j = 0; j < 8; j++) wr[j] = Ws[kk][tx + 16 * j];
#pragma unroll
            for (int i = 0; i < 4; i++)
#pragma unroll
                for (int j = 0; j < 8; j++) acc[i][j] = fmaf(xr[i], wr[j], acc[i][j]);
        }
        __syncthreads();
    }
#pragma unroll
    for (int i = 0; i < 4; i++) {
        int gr = rowbase + ty + 16 * i;
        if (gr < M) {
#pragma unroll
            for (int j = 0; j < 8; j++) H[(size_t)gr * 128 + tx + 16 * j] = acc[i][j];
        }
    }
}

// ---------------- aggregation: out[v] = dinv[v] * sum_{s in N(v)} h[s]*dinv[s] + b ----------------

__global__ __launch_bounds__(128) void k_agg(const float* __restrict__ h,
                                             const int* __restrict__ offs,
                                             const int* __restrict__ col,
                                             const float* __restrict__ dinv,
                                             const float* __restrict__ bias,
                                             float* __restrict__ out, int n, int do_relu) {
    int v = blockIdx.x;
    if (v >= n) return;
    int f = threadIdx.x;
    int e0 = offs[v], e1 = offs[v + 1];
    float acc = 0.f;
    for (int e = e0; e < e1; e++) {
        int s = col[e];
        acc += h[(size_t)s * 128 + f] * dinv[s];
    }
    float r = acc * dinv[v] + bias[f];
    if (do_relu) r = fmaxf(r, 0.f);
    out[(size_t)v * 128 + f] = r;
}

// ---------------- classifier + log_softmax: out[v,16] ----------------
// block 256 = 16 nodes x 16 class-lanes

__global__ __launch_bounds__(256) void k_classify(const float* __restrict__ h,
                                                  const float* __restrict__ Wc,
                                                  const float* __restrict__ bc,
                                                  float* __restrict__ out, int n) {
    __shared__ float Ws[128 * 16];
    int tid = threadIdx.x;
#pragma unroll
    for (int t = 0; t < 8; t++) Ws[tid + 256 * t] = Wc[tid + 256 * t];
    __syncthreads();

    int g = tid >> 4;   // node within block
    int j = tid & 15;   // class
    int v = blockIdx.x * 16 + g;
    if (v >= n) return;

    float acc = bc[j];
    const float* hv = h + (size_t)v * 128;
    for (int k = 0; k < 128; k++) acc = fmaf(hv[k], Ws[k * 16 + j], acc);

    float m = acc;
#pragma unroll
    for (int o = 8; o >= 1; o >>= 1) m = fmaxf(m, __shfl_xor(m, o, 16));
    float s = expf(acc - m);
#pragma unroll
    for (int o = 8; o >= 1; o >>= 1) s += __shfl_xor(s, o, 16);
    out[(size_t)v * 16 + j] = acc - m - logf(s);
}

// ---------------- launch ----------------

extern "C" void kernel_launch(void* const* d_in, const int* in_sizes, int n_in,
                              void* d_out, int out_size, void* d_ws, size_t ws_size,
                              hipStream_t stream) {
    const float* x  = (const float*)d_in[0];
    const int* eidx = (const int*)d_in[1];
    const float* W1 = (const float*)d_in[2];
    const float* b1 = (const float*)d_in[3];
    const float* W2 = (const float*)d_in[4];
    const float* b2 = (const float*)d_in[5];
    const float* Wc = (const float*)d_in[6];
    const float* bc = (const float*)d_in[7];
    float* out = (float*)d_out;

    const int N = in_sizes[0] / NFEAT;   // 50000
    const int E = in_sizes[1] / 2;       // 800000
    const int* src = eidx;
    const int* dst = eidx + E;

    // workspace carve-up
    char* p = (char*)d_ws;
    auto alloc = [&](size_t bytes) { char* r = p; p += (bytes + 255) & ~(size_t)255; return r; };
    int*   deg    = (int*)  alloc((size_t)N * 4);
    float* dinv   = (float*)alloc((size_t)N * 4);
    int*   offs   = (int*)  alloc((size_t)(N + 1) * 4);
    int*   cursor = (int*)  alloc((size_t)N * 4);
    int*   col    = (int*)  alloc((size_t)(E + N) * 4);
    int*   bsum   = (int*)  alloc((size_t)256 * 4);
    float* hA     = (float*)alloc((size_t)N * NHID * 4);
    float* hB     = (float*)alloc((size_t)N * NHID * 4);

    const int nb = (N + SCAN_BS - 1) / SCAN_BS;

    k_init_deg<<<(N + 255) / 256, 256, 0, stream>>>(deg, N);
    k_count<<<(E + 255) / 256, 256, 0, stream>>>(dst, E, deg);
    k_dinv<<<(N + 255) / 256, 256, 0, stream>>>(deg, dinv, cursor, N);
    k_scan1<<<nb, SCAN_BS, 0, stream>>>(deg, offs, bsum, N);
    k_scan2<<<1, 64, 0, stream>>>(bsum, offs, nb, N);
    k_scan3<<<nb, SCAN_BS, 0, stream>>>(offs, bsum, N);
    k_fill_edges<<<(E + 255) / 256, 256, 0, stream>>>(src, dst, E, offs, cursor, col);
    k_fill_self<<<(N + 255) / 256, 256, 0, stream>>>(offs, cursor, col, N);

    const int gblocks = (N + 63) / 64;
    // layer 1: hA = x @ W1 ; hB = agg(hA) + b1, relu
    k_gemm<<<gblocks, 256, 0, stream>>>(x, W1, hA, N, NFEAT);
    k_agg<<<N, 128, 0, stream>>>(hA, offs, col, dinv, b1, hB, N, 1);
    // layer 2: hA = hB @ W2 ; hB = agg(hA) + b2, relu
    k_gemm<<<gblocks, 256, 0, stream>>>(hB, W2, hA, N, NHID);
    k_agg<<<N, 128, 0, stream>>>(hA, offs, col, dinv, b2, hB, N, 1);
    // classifier + log_softmax
    k_classify<<<(N + 15) / 16, 256, 0, stream>>>(hB, Wc, bc, out, N);
}

// Round 2
// 327.766 us; speedup vs baseline: 1.4294x; 1.4294x over previous
//
#include <hip/hip_runtime.h>
#include <math.h>

#define NFEAT 512
#define NHID  128
#define NCLASS 16
#define SCAN_BS 512

typedef __attribute__((ext_vector_type(8))) short short8;
typedef __attribute__((ext_vector_type(4))) float f32x4;

static __device__ __forceinline__ ushort f2b(float f) {
    union { float f; uint u; } v; v.f = f;
    uint r = v.u + 0x7FFFu + ((v.u >> 16) & 1u);   // round-to-nearest-even
    return (ushort)(r >> 16);
}
static __device__ __forceinline__ float b2f(uint bits) {
    union { uint u; float f; } v; v.u = bits << 16; return v.f;
}

// ---------------- CSR build ----------------

__global__ void k_init_deg(int* __restrict__ deg, int n) {
    int i = blockIdx.x * blockDim.x + threadIdx.x;
    if (i < n) deg[i] = 1;  // self-loop
}

__global__ void k_count(const int* __restrict__ dst, int e, int* __restrict__ deg) {
    int i = blockIdx.x * blockDim.x + threadIdx.x;
    if (i < e) atomicAdd(&deg[dst[i]], 1);
}

__global__ void k_dinv(const int* __restrict__ deg, float* __restrict__ dinv,
                       int* __restrict__ cursor, int n) {
    int i = blockIdx.x * blockDim.x + threadIdx.x;
    if (i < n) {
        dinv[i] = rsqrtf((float)deg[i]);
        cursor[i] = 0;
    }
}

__global__ void k_scan1(const int* __restrict__ deg, int* __restrict__ offs,
                        int* __restrict__ bsum, int n) {
    __shared__ int s[SCAN_BS];
    int t = threadIdx.x;
    int i = blockIdx.x * SCAN_BS + t;
    int v = (i < n) ? deg[i] : 0;
    s[t] = v;
    for (int off = 1; off < SCAN_BS; off <<= 1) {
        __syncthreads();
        int x = (t >= off) ? s[t - off] : 0;
        __syncthreads();
        s[t] += x;
    }
    __syncthreads();
    if (i < n) offs[i] = s[t] - v;
    if (t == SCAN_BS - 1) bsum[blockIdx.x] = s[t];
}

__global__ void k_scan2(int* __restrict__ bsum, int* __restrict__ offs, int nb, int n) {
    if (threadIdx.x == 0 && blockIdx.x == 0) {
        int run = 0;
        for (int b = 0; b < nb; b++) { int x = bsum[b]; bsum[b] = run; run += x; }
        offs[n] = run;
    }
}

__global__ void k_scan3(int* __restrict__ offs, const int* __restrict__ bsum, int n) {
    int i = blockIdx.x * SCAN_BS + threadIdx.x;
    if (i < n) offs[i] += bsum[blockIdx.x];
}

__global__ void k_fill_edges(const int* __restrict__ src, const int* __restrict__ dst, int e,
                             const int* __restrict__ offs, int* __restrict__ cursor,
                             int* __restrict__ col) {
    int i = blockIdx.x * blockDim.x + threadIdx.x;
    if (i < e) {
        int d = dst[i];
        int p = atomicAdd(&cursor[d], 1);
        col[offs[d] + p] = src[i];
    }
}

__global__ void k_fill_self(const int* __restrict__ offs, int* __restrict__ cursor,
                            int* __restrict__ col, int n) {
    int i = blockIdx.x * blockDim.x + threadIdx.x;
    if (i < n) {
        int p = atomicAdd(&cursor[i], 1);
        col[offs[i] + p] = i;
    }
}

// ---------------- weight transpose+cast: W[K][128] f32 -> WT[128][K] bf16 ----------------

__global__ void k_tcast(const float* __restrict__ W, ushort* __restrict__ WT, int K) {
    int idx = blockIdx.x * 256 + threadIdx.x;
    if (idx < K * 128) {
        int k = idx >> 7, c = idx & 127;
        WT[(size_t)c * K + k] = f2b(W[idx]);
    }
}

// ---------------- bf16 MFMA GEMM: H[M,128] = A[M,K] @ W[K,128], WT pre-transposed bf16 ----
// block 256 = 4 waves (2x2), tile 128x128, BK=32. Output bf16.

template<int A_F32>
__global__ __launch_bounds__(256) void k_gemm(const void* __restrict__ Aptr,
                                              const ushort* __restrict__ WT,
                                              ushort* __restrict__ H, int M, int K) {
    __shared__ ushort As[128][40];  // pad 40: <=2-way bank conflict (free)
    __shared__ ushort Bs[128][40];

    const int tid = threadIdx.x;
    const int wid = tid >> 6, lane = tid & 63;
    const int wr = wid >> 1, wc = wid & 1;
    const int lr = lane & 15, lk = (lane >> 4) * 8;
    const int rowbase = blockIdx.x * 128;

    f32x4 acc[4][4];
#pragma unroll
    for (int i = 0; i < 4; i++)
#pragma unroll
        for (int j = 0; j < 4; j++) acc[i][j] = (f32x4)0.f;

    const int sr = tid >> 1;        // staging row 0..127
    const int sh = (tid & 1) * 16;  // staging half (16 elems)

    for (int k0 = 0; k0 < K; k0 += 32) {
        // ---- stage A (cvt to bf16 if f32) ----
        {
            int gr = rowbase + sr;
            ushort tmp[16];
            if (A_F32) {
                const float* A = (const float*)Aptr;
                if (gr < M) {
                    const float* p = A + (size_t)gr * K + k0 + sh;
#pragma unroll
                    for (int q = 0; q < 4; q++) {
                        float4 v = *(const float4*)(p + q * 4);
                        tmp[q * 4 + 0] = f2b(v.x); tmp[q * 4 + 1] = f2b(v.y);
                        tmp[q * 4 + 2] = f2b(v.z); tmp[q * 4 + 3] = f2b(v.w);
                    }
                } else {
#pragma unroll
                    for (int q = 0; q < 16; q++) tmp[q] = 0;
                }
            } else {
                const ushort* A = (const ushort*)Aptr;
                if (gr < M) {
                    const ushort* p = A + (size_t)gr * K + k0 + sh;
                    *(short8*)&tmp[0] = *(const short8*)(p);
                    *(short8*)&tmp[8] = *(const short8*)(p + 8);
                } else {
#pragma unroll
                    for (int q = 0; q < 16; q++) tmp[q] = 0;
                }
            }
            *(short8*)&As[sr][sh]     = *(short8*)&tmp[0];
            *(short8*)&As[sr][sh + 8] = *(short8*)&tmp[8];
        }
        // ---- stage B from WT[128][K]: rows=out-col, need [c][k0:k0+32] ----
        {
#pragma unroll
            for (int t = 0; t < 2; t++) {
                int c = tid + t * 256;         // chunk 0..511
                int row = c >> 2, q = c & 3;
                short8 v = *(const short8*)(WT + (size_t)row * K + k0 + q * 8);
                *(short8*)&Bs[row][q * 8] = v;
            }
        }
        __syncthreads();

        short8 af[4], bfv[4];
#pragma unroll
        for (int i = 0; i < 4; i++) af[i] = *(const short8*)&As[wr * 64 + i * 16 + lr][lk];
#pragma unroll
        for (int j = 0; j < 4; j++) bfv[j] = *(const short8*)&Bs[wc * 64 + j * 16 + lr][lk];
#pragma unroll
        for (int i = 0; i < 4; i++)
#pragma unroll
            for (int j = 0; j < 4; j++)
                acc[i][j] = __builtin_amdgcn_mfma_f32_16x16x32_bf16(af[i], bfv[j], acc[i][j], 0, 0, 0);
        __syncthreads();
    }

    // epilogue: row = (lane>>4)*4 + r, col = lane&15 within each 16x16 frag
#pragma unroll
    for (int i = 0; i < 4; i++) {
#pragma unroll
        for (int r = 0; r < 4; r++) {
            int row = rowbase + wr * 64 + i * 16 + (lane >> 4) * 4 + r;
            if (row < M) {
#pragma unroll
                for (int j = 0; j < 4; j++) {
                    int colg = wc * 64 + j * 16 + lr;
                    H[(size_t)row * 128 + colg] = f2b(acc[i][j][r]);
                }
            }
        }
    }
}

// ---------------- aggregation: wave per node, bf16 input rows ----------------
// out[v] = relu?( dinv[v] * sum_{s in N(v)} h[s]*dinv[s] + b )

template<int OUT_BF16>
__global__ __launch_bounds__(256) void k_agg(const ushort* __restrict__ h,
                                             const int* __restrict__ offs,
                                             const int* __restrict__ col,
                                             const float* __restrict__ dinv,
                                             const float* __restrict__ bias,
                                             void* __restrict__ outp, int n) {
    int wid = threadIdx.x >> 6, lane = threadIdx.x & 63;
    int v = blockIdx.x * 4 + wid;
    if (v >= n) return;
    int e0 = offs[v], e1 = offs[v + 1];
    float a0 = 0.f, a1 = 0.f;
    for (int e = e0; e < e1; e++) {
        int s = col[e];
        float dv = dinv[s];
        uint pk = *(const uint*)(h + (size_t)s * 128 + lane * 2);
        a0 = fmaf(b2f(pk & 0xffffu), dv, a0);
        a1 = fmaf(b2f(pk >> 16), dv, a1);
    }
    float dvv = dinv[v];
    float r0 = fmaxf(fmaf(a0, dvv, bias[lane * 2 + 0]), 0.f);
    float r1 = fmaxf(fmaf(a1, dvv, bias[lane * 2 + 1]), 0.f);
    if (OUT_BF16) {
        uint pk = (uint)f2b(r0) | ((uint)f2b(r1) << 16);
        *(uint*)((ushort*)outp + (size_t)v * 128 + lane * 2) = pk;
    } else {
        *(float2*)((float*)outp + (size_t)v * 128 + lane * 2) = make_float2(r0, r1);
    }
}

// ---------------- classifier + log_softmax ----------------

__global__ __launch_bounds__(256) void k_classify(const float* __restrict__ h,
                                                  const float* __restrict__ Wc,
                                                  const float* __restrict__ bc,
                                                  float* __restrict__ out, int n) {
    __shared__ float Ws[128 * 16];
    int tid = threadIdx.x;
#pragma unroll
    for (int t = 0; t < 8; t++) Ws[tid + 256 * t] = Wc[tid + 256 * t];
    __syncthreads();

    int g = tid >> 4;
    int j = tid & 15;
    int v = blockIdx.x * 16 + g;
    if (v >= n) return;

    float acc = bc[j];
    const float* hv = h + (size_t)v * 128;
    for (int k = 0; k < 128; k++) acc = fmaf(hv[k], Ws[k * 16 + j], acc);

    float m = acc;
#pragma unroll
    for (int o = 8; o >= 1; o >>= 1) m = fmaxf(m, __shfl_xor(m, o, 16));
    float s = expf(acc - m);
#pragma unroll
    for (int o = 8; o >= 1; o >>= 1) s += __shfl_xor(s, o, 16);
    out[(size_t)v * 16 + j] = acc - m - logf(s);
}

// ---------------- launch ----------------

extern "C" void kernel_launch(void* const* d_in, const int* in_sizes, int n_in,
                              void* d_out, int out_size, void* d_ws, size_t ws_size,
                              hipStream_t stream) {
    const float* x  = (const float*)d_in[0];
    const int* eidx = (const int*)d_in[1];
    const float* W1 = (const float*)d_in[2];
    const float* b1 = (const float*)d_in[3];
    const float* W2 = (const float*)d_in[4];
    const float* b2 = (const float*)d_in[5];
    const float* Wc = (const float*)d_in[6];
    const float* bc = (const float*)d_in[7];
    float* out = (float*)d_out;

    const int N = in_sizes[0] / NFEAT;   // 50000
    const int E = in_sizes[1] / 2;       // 800000
    const int* src = eidx;
    const int* dst = eidx + E;

    char* p = (char*)d_ws;
    auto alloc = [&](size_t bytes) { char* r = p; p += (bytes + 255) & ~(size_t)255; return r; };
    int*    deg    = (int*)   alloc((size_t)N * 4);
    float*  dinv   = (float*) alloc((size_t)N * 4);
    int*    offs   = (int*)   alloc((size_t)(N + 1) * 4);
    int*    cursor = (int*)   alloc((size_t)N * 4);
    int*    col    = (int*)   alloc((size_t)(E + N) * 4);
    int*    bsum   = (int*)   alloc((size_t)256 * 4);
    ushort* W1T    = (ushort*)alloc((size_t)128 * NFEAT * 2);
    ushort* W2T    = (ushort*)alloc((size_t)128 * NHID * 2);
    ushort* bufA   = (ushort*)alloc((size_t)N * NHID * 2);   // h1b then h2b
    float*  bufB   = (float*) alloc((size_t)N * NHID * 4);   // g1b (bf16, first half) then g2f (f32)
    ushort* g1b    = (ushort*)bufB;

    const int nb = (N + SCAN_BS - 1) / SCAN_BS;

    k_init_deg<<<(N + 255) / 256, 256, 0, stream>>>(deg, N);
    k_count<<<(E + 255) / 256, 256, 0, stream>>>(dst, E, deg);
    k_dinv<<<(N + 255) / 256, 256, 0, stream>>>(deg, dinv, cursor, N);
    k_scan1<<<nb, SCAN_BS, 0, stream>>>(deg, offs, bsum, N);
    k_scan2<<<1, 64, 0, stream>>>(bsum, offs, nb, N);
    k_scan3<<<nb, SCAN_BS, 0, stream>>>(offs, bsum, N);
    k_fill_edges<<<(E + 255) / 256, 256, 0, stream>>>(src, dst, E, offs, cursor, col);
    k_fill_self<<<(N + 255) / 256, 256, 0, stream>>>(offs, cursor, col, N);

    k_tcast<<<(NFEAT * 128 + 255) / 256, 256, 0, stream>>>(W1, W1T, NFEAT);
    k_tcast<<<(NHID * 128 + 255) / 256, 256, 0, stream>>>(W2, W2T, NHID);

    const int gblocks = (N + 127) / 128;
    // layer 1
    k_gemm<1><<<gblocks, 256, 0, stream>>>(x, W1T, bufA, N, NFEAT);
    k_agg<1><<<(N + 3) / 4, 256, 0, stream>>>(bufA, offs, col, dinv, b1, g1b, N);
    // layer 2
    k_gemm<0><<<gblocks, 256, 0, stream>>>(g1b, W2T, bufA, N, NHID);
    k_agg<0><<<(N + 3) / 4, 256, 0, stream>>>(bufA, offs, col, dinv, b2, bufB, N);
    // classifier
    k_classify<<<(N + 15) / 16, 256, 0, stream>>>(bufB, Wc, bc, out, N);
}

// Round 3
// 241.181 us; speedup vs baseline: 1.9426x; 1.3590x over previous
//
#include <hip/hip_runtime.h>
#include <math.h>

#define NFEAT 512
#define NHID  128
#define NCLASS 16
#define SCAN_BS 512

typedef __attribute__((ext_vector_type(8))) short short8;
typedef __attribute__((ext_vector_type(4))) float f32x4;

static __device__ __forceinline__ ushort f2b(float f) {
    union { float f; uint u; } v; v.f = f;
    uint r = v.u + 0x7FFFu + ((v.u >> 16) & 1u);   // round-to-nearest-even
    return (ushort)(r >> 16);
}
static __device__ __forceinline__ float b2f(uint bits) {
    union { uint u; float f; } v; v.u = bits << 16; return v.f;
}

// ---------------- CSR build ----------------

__global__ void k_init_deg(int* __restrict__ deg, int n) {
    int i = blockIdx.x * blockDim.x + threadIdx.x;
    if (i < n) deg[i] = 1;  // self-loop
}

__global__ void k_count(const int* __restrict__ dst, int e, int* __restrict__ deg) {
    int i = blockIdx.x * blockDim.x + threadIdx.x;
    if (i < e) atomicAdd(&deg[dst[i]], 1);
}

__global__ void k_dinv(const int* __restrict__ deg, float* __restrict__ dinv,
                       int* __restrict__ cursor, int n) {
    int i = blockIdx.x * blockDim.x + threadIdx.x;
    if (i < n) {
        dinv[i] = rsqrtf((float)deg[i]);
        cursor[i] = 0;
    }
}

__global__ void k_scan1(const int* __restrict__ deg, int* __restrict__ offs,
                        int* __restrict__ bsum, int n) {
    __shared__ int s[SCAN_BS];
    int t = threadIdx.x;
    int i = blockIdx.x * SCAN_BS + t;
    int v = (i < n) ? deg[i] : 0;
    s[t] = v;
    for (int off = 1; off < SCAN_BS; off <<= 1) {
        __syncthreads();
        int x = (t >= off) ? s[t - off] : 0;
        __syncthreads();
        s[t] += x;
    }
    __syncthreads();
    if (i < n) offs[i] = s[t] - v;
    if (t == SCAN_BS - 1) bsum[blockIdx.x] = s[t];
}

__global__ void k_scan2(int* __restrict__ bsum, int* __restrict__ offs, int nb, int n) {
    if (threadIdx.x == 0 && blockIdx.x == 0) {
        int run = 0;
        for (int b = 0; b < nb; b++) { int x = bsum[b]; bsum[b] = run; run += x; }
        offs[n] = run;
    }
}

__global__ void k_scan3(int* __restrict__ offs, const int* __restrict__ bsum, int n) {
    int i = blockIdx.x * SCAN_BS + threadIdx.x;
    if (i < n) offs[i] += bsum[blockIdx.x];
}

__global__ void k_fill_edges(const int* __restrict__ src, const int* __restrict__ dst, int e,
                             const int* __restrict__ offs, int* __restrict__ cursor,
                             int* __restrict__ col) {
    int i = blockIdx.x * blockDim.x + threadIdx.x;
    if (i < e) {
        int d = dst[i];
        int p = atomicAdd(&cursor[d], 1);
        col[offs[d] + p] = src[i];
    }
}

__global__ void k_fill_self(const int* __restrict__ offs, int* __restrict__ cursor,
                            int* __restrict__ col, int n) {
    int i = blockIdx.x * blockDim.x + threadIdx.x;
    if (i < n) {
        int p = atomicAdd(&cursor[i], 1);
        col[offs[i] + p] = i;
    }
}

// ---------------- weight transpose+cast: W[K][128] f32 -> WT[128][K] bf16 ----------------

__global__ void k_tcast(const float* __restrict__ W, ushort* __restrict__ WT, int K) {
    int idx = blockIdx.x * 256 + threadIdx.x;
    if (idx < K * 128) {
        int k = idx >> 7, c = idx & 127;
        WT[(size_t)c * K + k] = f2b(W[idx]);
    }
}

// ---------------- bf16 MFMA GEMM: H[M,128] = (A[M,K] @ W[K,128]) * rowscale[row] ----
// block 256 = 4 waves (2x2), tile 128x128, BK=32. Output bf16, pre-scaled by dinv[row].

template<int A_F32>
__global__ __launch_bounds__(256) void k_gemm(const void* __restrict__ Aptr,
                                              const ushort* __restrict__ WT,
                                              const float* __restrict__ rowscale,
                                              ushort* __restrict__ H, int M, int K) {
    __shared__ ushort As[128][40];  // pad 40: <=2-way bank conflict (free)
    __shared__ ushort Bs[128][40];

    const int tid = threadIdx.x;
    const int wid = tid >> 6, lane = tid & 63;
    const int wr = wid >> 1, wc = wid & 1;
    const int lr = lane & 15, lk = (lane >> 4) * 8;
    const int rowbase = blockIdx.x * 128;

    f32x4 acc[4][4];
#pragma unroll
    for (int i = 0; i < 4; i++)
#pragma unroll
        for (int j = 0; j < 4; j++) acc[i][j] = (f32x4)0.f;

    const int sr = tid >> 1;        // staging row 0..127
    const int sh = (tid & 1) * 16;  // staging half (16 elems)

    for (int k0 = 0; k0 < K; k0 += 32) {
        // ---- stage A (cvt to bf16 if f32) ----
        {
            int gr = rowbase + sr;
            ushort tmp[16];
            if (A_F32) {
                const float* A = (const float*)Aptr;
                if (gr < M) {
                    const float* p = A + (size_t)gr * K + k0 + sh;
#pragma unroll
                    for (int q = 0; q < 4; q++) {
                        float4 v = *(const float4*)(p + q * 4);
                        tmp[q * 4 + 0] = f2b(v.x); tmp[q * 4 + 1] = f2b(v.y);
                        tmp[q * 4 + 2] = f2b(v.z); tmp[q * 4 + 3] = f2b(v.w);
                    }
                } else {
#pragma unroll
                    for (int q = 0; q < 16; q++) tmp[q] = 0;
                }
            } else {
                const ushort* A = (const ushort*)Aptr;
                if (gr < M) {
                    const ushort* p = A + (size_t)gr * K + k0 + sh;
                    *(short8*)&tmp[0] = *(const short8*)(p);
                    *(short8*)&tmp[8] = *(const short8*)(p + 8);
                } else {
#pragma unroll
                    for (int q = 0; q < 16; q++) tmp[q] = 0;
                }
            }
            *(short8*)&As[sr][sh]     = *(short8*)&tmp[0];
            *(short8*)&As[sr][sh + 8] = *(short8*)&tmp[8];
        }
        // ---- stage B from WT[128][K] ----
        {
#pragma unroll
            for (int t = 0; t < 2; t++) {
                int c = tid + t * 256;
                int row = c >> 2, q = c & 3;
                short8 v = *(const short8*)(WT + (size_t)row * K + k0 + q * 8);
                *(short8*)&Bs[row][q * 8] = v;
            }
        }
        __syncthreads();

        short8 af[4], bfv[4];
#pragma unroll
        for (int i = 0; i < 4; i++) af[i] = *(const short8*)&As[wr * 64 + i * 16 + lr][lk];
#pragma unroll
        for (int j = 0; j < 4; j++) bfv[j] = *(const short8*)&Bs[wc * 64 + j * 16 + lr][lk];
#pragma unroll
        for (int i = 0; i < 4; i++)
#pragma unroll
            for (int j = 0; j < 4; j++)
                acc[i][j] = __builtin_amdgcn_mfma_f32_16x16x32_bf16(af[i], bfv[j], acc[i][j], 0, 0, 0);
        __syncthreads();
    }

#pragma unroll
    for (int i = 0; i < 4; i++) {
#pragma unroll
        for (int r = 0; r < 4; r++) {
            int row = rowbase + wr * 64 + i * 16 + (lane >> 4) * 4 + r;
            if (row < M) {
                float sc = rowscale[row];
#pragma unroll
                for (int j = 0; j < 4; j++) {
                    int colg = wc * 64 + j * 16 + lr;
                    H[(size_t)row * 128 + colg] = f2b(acc[i][j][r] * sc);
                }
            }
        }
    }
}

// ---------------- aggregation: wave per node, 8 gathers in flight ----------------
// h rows are pre-scaled by dinv[src]; out[v] = relu( dinv[v]*sum h'[s] + b )

template<int OUT_BF16>
__global__ __launch_bounds__(256) void k_agg(const ushort* __restrict__ h,
                                             const int* __restrict__ offs,
                                             const int* __restrict__ col,
                                             const float* __restrict__ dinv,
                                             const float* __restrict__ bias,
                                             void* __restrict__ outp, int n) {
    int wid = threadIdx.x >> 6, lane = threadIdx.x & 63;
    int v = blockIdx.x * 4 + wid;
    if (v >= n) return;
    int e0 = offs[v], e1 = offs[v + 1];
    int lx = lane * 2;
    float a0 = 0.f, a1 = 0.f;
    for (int base = e0; base < e1; base += 64) {
        int cnt = e1 - base; if (cnt > 64) cnt = 64;
        int myc = 0;
        if (base + lane < e1) myc = col[base + lane];
        int j = 0;
        for (; j + 8 <= cnt; j += 8) {
            uint pk[8];
#pragma unroll
            for (int q = 0; q < 8; q++) {
                int s = __shfl(myc, j + q);
                pk[q] = *(const uint*)(h + (size_t)s * 128 + lx);
            }
#pragma unroll
            for (int q = 0; q < 8; q++) {
                a0 += b2f(pk[q] & 0xffffu);
                a1 += b2f(pk[q] >> 16);
            }
        }
        for (; j < cnt; j++) {
            int s = __shfl(myc, j);
            uint p0 = *(const uint*)(h + (size_t)s * 128 + lx);
            a0 += b2f(p0 & 0xffffu);
            a1 += b2f(p0 >> 16);
        }
    }
    float dvv = dinv[v];
    float r0 = fmaxf(fmaf(a0, dvv, bias[lx + 0]), 0.f);
    float r1 = fmaxf(fmaf(a1, dvv, bias[lx + 1]), 0.f);
    if (OUT_BF16) {
        uint pk = (uint)f2b(r0) | ((uint)f2b(r1) << 16);
        *(uint*)((ushort*)outp + (size_t)v * 128 + lx) = pk;
    } else {
        *(float2*)((float*)outp + (size_t)v * 128 + lx) = make_float2(r0, r1);
    }
}

// ---------------- classifier + log_softmax ----------------

__global__ __launch_bounds__(256) void k_classify(const float* __restrict__ h,
                                                  const float* __restrict__ Wc,
                                                  const float* __restrict__ bc,
                                                  float* __restrict__ out, int n) {
    __shared__ float Ws[128 * 16];
    int tid = threadIdx.x;
#pragma unroll
    for (int t = 0; t < 8; t++) Ws[tid + 256 * t] = Wc[tid + 256 * t];
    __syncthreads();

    int g = tid >> 4;
    int j = tid & 15;
    int v = blockIdx.x * 16 + g;
    if (v >= n) return;

    float acc = bc[j];
    const float* hv = h + (size_t)v * 128;
    for (int k = 0; k < 128; k++) acc = fmaf(hv[k], Ws[k * 16 + j], acc);

    float m = acc;
#pragma unroll
    for (int o = 8; o >= 1; o >>= 1) m = fmaxf(m, __shfl_xor(m, o, 16));
    float s = expf(acc - m);
#pragma unroll
    for (int o = 8; o >= 1; o >>= 1) s += __shfl_xor(s, o, 16);
    out[(size_t)v * 16 + j] = acc - m - logf(s);
}

// ---------------- launch ----------------

extern "C" void kernel_launch(void* const* d_in, const int* in_sizes, int n_in,
                              void* d_out, int out_size, void* d_ws, size_t ws_size,
                              hipStream_t stream) {
    const float* x  = (const float*)d_in[0];
    const int* eidx = (const int*)d_in[1];
    const float* W1 = (const float*)d_in[2];
    const float* b1 = (const float*)d_in[3];
    const float* W2 = (const float*)d_in[4];
    const float* b2 = (const float*)d_in[5];
    const float* Wc = (const float*)d_in[6];
    const float* bc = (const float*)d_in[7];
    float* out = (float*)d_out;

    const int N = in_sizes[0] / NFEAT;   // 50000
    const int E = in_sizes[1] / 2;       // 800000
    const int* src = eidx;
    const int* dst = eidx + E;

    char* p = (char*)d_ws;
    auto alloc = [&](size_t bytes) { char* r = p; p += (bytes + 255) & ~(size_t)255; return r; };
    int*    deg    = (int*)   alloc((size_t)N * 4);
    float*  dinv   = (float*) alloc((size_t)N * 4);
    int*    offs   = (int*)   alloc((size_t)(N + 1) * 4);
    int*    cursor = (int*)   alloc((size_t)N * 4);
    int*    col    = (int*)   alloc((size_t)(E + N) * 4);
    int*    bsum   = (int*)   alloc((size_t)256 * 4);
    ushort* W1T    = (ushort*)alloc((size_t)128 * NFEAT * 2);
    ushort* W2T    = (ushort*)alloc((size_t)128 * NHID * 2);
    ushort* bufA   = (ushort*)alloc((size_t)N * NHID * 2);   // h1' then h2'
    float*  bufB   = (float*) alloc((size_t)N * NHID * 4);   // g1 (bf16, first half) then g2 (f32)
    ushort* g1b    = (ushort*)bufB;

    const int nb = (N + SCAN_BS - 1) / SCAN_BS;

    k_init_deg<<<(N + 255) / 256, 256, 0, stream>>>(deg, N);
    k_count<<<(E + 255) / 256, 256, 0, stream>>>(dst, E, deg);
    k_dinv<<<(N + 255) / 256, 256, 0, stream>>>(deg, dinv, cursor, N);
    k_scan1<<<nb, SCAN_BS, 0, stream>>>(deg, offs, bsum, N);
    k_scan2<<<1, 64, 0, stream>>>(bsum, offs, nb, N);
    k_scan3<<<nb, SCAN_BS, 0, stream>>>(offs, bsum, N);
    k_fill_edges<<<(E + 255) / 256, 256, 0, stream>>>(src, dst, E, offs, cursor, col);
    k_fill_self<<<(N + 255) / 256, 256, 0, stream>>>(offs, cursor, col, N);

    k_tcast<<<(NFEAT * 128 + 255) / 256, 256, 0, stream>>>(W1, W1T, NFEAT);
    k_tcast<<<(NHID * 128 + 255) / 256, 256, 0, stream>>>(W2, W2T, NHID);

    const int gblocks = (N + 127) / 128;
    // layer 1
    k_gemm<1><<<gblocks, 256, 0, stream>>>(x, W1T, dinv, bufA, N, NFEAT);
    k_agg<1><<<(N + 3) / 4, 256, 0, stream>>>(bufA, offs, col, dinv, b1, g1b, N);
    // layer 2
    k_gemm<0><<<gblocks, 256, 0, stream>>>(g1b, W2T, dinv, bufA, N, NHID);
    k_agg<0><<<(N + 3) / 4, 256, 0, stream>>>(bufA, offs, col, dinv, b2, bufB, N);
    // classifier
    k_classify<<<(N + 15) / 16, 256, 0, stream>>>(bufB, Wc, bc, out, N);
}